// Round 1
// baseline (682.273 us; speedup 1.0000x reference)
//
#include <hip/hip_runtime.h>
#include <hip/hip_bf16.h>

typedef unsigned short u16;
typedef __bf16 bf16x8 __attribute__((ext_vector_type(8)));
typedef float f32x4 __attribute__((ext_vector_type(4)));

__device__ __forceinline__ float bf2f(u16 u) {
  union { unsigned int u; float f; } x; x.u = ((unsigned int)u) << 16; return x.f;
}
__device__ __forceinline__ u16 f2bf(float f) {  // round-to-nearest-even bf16
  union { float f; unsigned int u; } x; x.f = f;
  unsigned int r = x.u + 0x7fffu + ((x.u >> 16) & 1u);
  return (u16)(r >> 16);
}

__device__ __forceinline__ void gload16(const void* g, void* l) {
  __builtin_amdgcn_global_load_lds((__attribute__((address_space(1))) void*)g,
                                   (__attribute__((address_space(3))) void*)l, 16, 0, 0);
}

// ---------------------------------------------------------------------------
// Generic NT GEMM: C[m,n] = sum_k A[m,k]*B[n,k], bf16 inputs, f32 accum.
// 128x128 tile, BK=32, 256 threads (4 waves, 2x2 of 64x64), m97 structure.
// EPI: 0 = f32 store to C
//      1 = bf16 exp(clip(v,-10,10)) to Cb            (layer-1 T)
//      2 = bf16 gelu_exact(v) to Cb                  (FF1)
//      3 = f32 to C (ldc=512, padded 2176 rows) + bf16 pack rows s<512 to Cb (FF2)
// zmode 0: aoff=z*aZ boff=z*bZ   zmode 1: aoff=(z&7)*aZ boff=(z>>3)*bZ  (b,h batch)
// ---------------------------------------------------------------------------
template<int EPI>
__global__ __launch_bounds__(256) void gemm_nt(
    const u16* __restrict__ A, const u16* __restrict__ B,
    float* __restrict__ C, u16* __restrict__ Cb,
    int lda, int ldb, int ldc, int ksteps,
    long aZ, long bZ, long cZ, int zmode)
{
  __shared__ u16 sA[128 * 32];
  __shared__ u16 sB[128 * 32];
  const int t = threadIdx.x;
  const int mbase = blockIdx.x * 128;
  const int nbase = blockIdx.y * 128;
  const int z = blockIdx.z;
  long aoff, boff;
  if (zmode == 1) { aoff = (long)(z & 7) * aZ; boff = (long)(z >> 3) * bZ; }
  else            { aoff = (long)z * aZ;       boff = (long)z * bZ; }
  const long coff = (long)z * cZ;
  const u16* Ab = A + aoff + (long)mbase * lda;
  const u16* Bb = B + boff + (long)nbase * ldb;

  const int srow = t >> 2;          // staging row 0..63 (per 64-row chunk)
  const int scol = (t & 3) * 8;     // staging k-offset (elements)
  const int lane = t & 63;
  const int w = t >> 6;
  const int wrow = (w >> 1) * 64;
  const int wcol = (w & 1) * 64;
  const int fr  = lane & 15;        // fragment row/col
  const int fko = (lane >> 4) * 8;  // fragment k element offset

  f32x4 acc[4][4];
  #pragma unroll
  for (int m = 0; m < 4; ++m)
    #pragma unroll
    for (int n = 0; n < 4; ++n) acc[m][n] = (f32x4){0.f, 0.f, 0.f, 0.f};

  for (int ks = 0; ks < ksteps; ++ks) {
    const int kb = ks * 32;
    #pragma unroll
    for (int c = 0; c < 2; ++c) {
      // LDS dest is linear: byte off = c*4096 + t*16 (wave-uniform base + lane*16)
      gload16(Ab + (long)(c * 64 + srow) * lda + kb + scol, &sA[(c * 64 + srow) * 32 + scol]);
      gload16(Bb + (long)(c * 64 + srow) * ldb + kb + scol, &sB[(c * 64 + srow) * 32 + scol]);
    }
    __syncthreads();
    bf16x8 af[4], bfg[4];
    #pragma unroll
    for (int m = 0; m < 4; ++m) af[m]  = *(const bf16x8*)&sA[(wrow + m * 16 + fr) * 32 + fko];
    #pragma unroll
    for (int n = 0; n < 4; ++n) bfg[n] = *(const bf16x8*)&sB[(wcol + n * 16 + fr) * 32 + fko];
    #pragma unroll
    for (int m = 0; m < 4; ++m)
      #pragma unroll
      for (int n = 0; n < 4; ++n)
        acc[m][n] = __builtin_amdgcn_mfma_f32_16x16x32_bf16(af[m], bfg[n], acc[m][n], 0, 0, 0);
    __syncthreads();
  }

  // C/D layout (m89-verified): col = lane&15, row = (lane>>4)*4 + j
  #pragma unroll
  for (int m = 0; m < 4; ++m) {
    const int r0 = mbase + wrow + m * 16 + (lane >> 4) * 4;
    #pragma unroll
    for (int n = 0; n < 4; ++n) {
      const int c = nbase + wcol + n * 16 + (lane & 15);
      #pragma unroll
      for (int j = 0; j < 4; ++j) {
        const float v = acc[m][n][j];
        const int r = r0 + j;
        const long idx = coff + (long)r * ldc + c;
        if (EPI == 0) {
          C[idx] = v;
        } else if (EPI == 1) {
          float cv = fminf(fmaxf(v, -10.f), 10.f);
          Cb[idx] = f2bf(__expf(cv));
        } else if (EPI == 2) {
          Cb[idx] = f2bf(0.5f * v * (1.f + erff(v * 0.70710678118654752f)));
        } else {
          C[(long)r * 512 + c] = v;            // f_k f32 (padded 2176 rows)
          int b = r / 513;
          int s = r - b * 513;
          if (r < 2052 && s < 512) Cb[((long)(b * 512 + s)) * 512 + c] = f2bf(v);
        }
      }
    }
  }
}

// --------- W_e prep: bf16 cast, transposed bf16 copy, column sums ----------
__global__ void prep_we_k(const float* __restrict__ We, u16* __restrict__ Web,
                          u16* __restrict__ WeT, float* __restrict__ colsum)
{
  __shared__ float tile[64][65];
  const int v0 = blockIdx.x * 64, d0 = blockIdx.y * 64;
  const int t = threadIdx.x;
  const int c = t & 63;
  #pragma unroll
  for (int rr = 0; rr < 64; rr += 4) {
    const int row = rr + (t >> 6);
    const float x = We[(long)(v0 + row) * 512 + d0 + c];
    Web[(long)(v0 + row) * 512 + d0 + c] = f2bf(x);
    tile[row][c] = x;
  }
  __syncthreads();
  #pragma unroll
  for (int rr = 0; rr < 64; rr += 4) {
    const int drow = rr + (t >> 6);
    WeT[(long)(d0 + drow) * 32000 + v0 + c] = f2bf(tile[c][drow]);
  }
  if (t < 64) {
    float s = 0.f;
    #pragma unroll
    for (int i = 0; i < 64; ++i) s += tile[i][t];
    atomicAdd(&colsum[d0 + t], s);
  }
}

__global__ void cast_k(const float* __restrict__ a, const float* __restrict__ b,
                       u16* __restrict__ ab, u16* __restrict__ bb, int n)
{
  const int i = blockIdx.x * 256 + threadIdx.x;
  if (i < n) { ab[i] = f2bf(a[i]); bb[i] = f2bf(b[i]); }
}

__global__ void gather_e_k(const int* __restrict__ x, const float* __restrict__ We,
                           float* __restrict__ e)
{
  const long r = blockIdx.x;
  const long v = x[r];
  const int t = threadIdx.x;
  e[r * 512 + t]       = We[v * 512 + t];
  e[r * 512 + t + 256] = We[v * 512 + t + 256];
}

__global__ void qkpack_k(const float* __restrict__ Wp, const float* __restrict__ Wq,
                         const float* __restrict__ Wk, u16* __restrict__ Qp,
                         u16* __restrict__ Kp)
{
  const int q = blockIdx.x;   // 0..512 (513 rows)
  const int h = blockIdx.y;
  const int t = threadIdx.x;
  #pragma unroll
  for (int j = 0; j < 2; ++j) {
    const int d = t + j * 256;
    const float pv = Wp[(long)q * 512 + d];
    Qp[((long)h * 640 + q) * 512 + d] = f2bf(pv * Wq[h * 512 + d]);
    if (q < 512) Kp[((long)h * 512 + q) * 512 + d] = f2bf(pv * Wk[h * 512 + d]);
  }
}

__global__ void softmax_k(const float* __restrict__ scores, u16* __restrict__ attn)
{
  const int q = blockIdx.x;   // 0..512
  const int h = blockIdx.y;
  const float* row = scores + ((long)h * 640 + q) * 512;
  u16* orow = attn + ((long)h * 640 + q) * 512;
  const int t = threadIdx.x;
  const float v0 = row[t], v1 = row[t + 256];
  __shared__ float red[4];
  float m = fmaxf(v0, v1);
  for (int o = 32; o; o >>= 1) m = fmaxf(m, __shfl_down(m, o, 64));
  if ((t & 63) == 0) red[t >> 6] = m;
  __syncthreads();
  m = fmaxf(fmaxf(red[0], red[1]), fmaxf(red[2], red[3]));
  __syncthreads();
  const float e0 = __expf(v0 - m), e1 = __expf(v1 - m);
  float s = e0 + e1;
  for (int o = 32; o; o >>= 1) s += __shfl_down(s, o, 64);
  if ((t & 63) == 0) red[t >> 6] = s;
  __syncthreads();
  s = red[0] + red[1] + red[2] + red[3];
  const float inv = 1.f / s;
  orow[t]       = f2bf(e0 * inv);
  orow[t + 256] = f2bf(e1 * inv);
}

__global__ void rowsumT_k(const u16* __restrict__ T, float* __restrict__ rowsum)
{
  const long r = blockIdx.x;
  const u16* row = T + r * 32000;
  const int t = threadIdx.x;
  float s = 0.f;
  for (int i = t * 8; i < 32000; i += 2048) {
    uint4 a = *(const uint4*)(row + i);
    const u16* pu = (const u16*)&a;
    #pragma unroll
    for (int j = 0; j < 8; ++j) s += bf2f(pu[j]);
  }
  __shared__ float red[4];
  for (int o = 32; o; o >>= 1) s += __shfl_down(s, o, 64);
  if ((t & 63) == 0) red[t >> 6] = s;
  __syncthreads();
  if (t == 0) rowsum[r] = red[0] + red[1] + red[2] + red[3];
}

// diff = e - E ; writes transposed bf16 diffT[b][d][s] and csum[b][d] (+=)
// USE_E=1: E from split-K partials / rowsum ; USE_E=0: E = colsum/32000 (layer 0)
template<int USE_E>
__global__ void diff_k(const float* __restrict__ e, const float* __restrict__ part,
                       const float* __restrict__ rowsum, const float* __restrict__ colsum,
                       u16* __restrict__ diffT, float* __restrict__ csum)
{
  __shared__ float tile[64][65];
  const int s0 = blockIdx.x * 64, d0 = blockIdx.y * 64, b = blockIdx.z;
  const int t = threadIdx.x;
  const int c = t & 63;
  #pragma unroll
  for (int rr = 0; rr < 64; rr += 4) {
    const int srow = rr + (t >> 6);
    const long r = (long)b * 512 + s0 + srow;
    float E;
    if (USE_E) {
      float s = 0.f;
      #pragma unroll
      for (int p = 0; p < 8; ++p) s += part[((long)p * 2048 + r) * 512 + d0 + c];
      E = s / (rowsum[r] + 1e-8f);
    } else {
      E = colsum[d0 + c] * (1.0f / 32000.0f);
    }
    tile[srow][c] = e[r * 512 + d0 + c] - E;
  }
  __syncthreads();
  #pragma unroll
  for (int rr = 0; rr < 64; rr += 4) {
    const int drow = rr + (t >> 6);
    diffT[((long)b * 512 + d0 + drow) * 512 + s0 + c] = f2bf(tile[c][drow]);
  }
  if (t < 64) {
    float s = 0.f;
    #pragma unroll
    for (int i = 0; i < 64; ++i) s += tile[i][t];
    atomicAdd(&csum[b * 512 + d0 + t], s);
  }
}

// v = f_k + delta/512 ; LayerNorm(v)*g -> bf16 h_pack row
__global__ void delta_ln_k(const float* __restrict__ Mh, const float* __restrict__ csum,
                           const float* __restrict__ fk, const float* __restrict__ Wv,
                           const float* __restrict__ Alr, const float* __restrict__ Blr,
                           const float* __restrict__ lng, u16* __restrict__ hout,
                           int l, int use_fk)
{
  const int q = blockIdx.x;    // 0..512
  const int b = blockIdx.y;
  const long r = (long)b * 513 + q;
  const int t = threadIdx.x;
  __shared__ float red[4];
  float v[2];
  #pragma unroll
  for (int j = 0; j < 2; ++j) {
    const int d = t + j * 256;
    float acc = Blr[l] * csum[b * 512 + d];
    #pragma unroll
    for (int h = 0; h < 8; ++h)
      acc += Alr[l * 8 + h] * Wv[(l * 8 + h) * 512 + d] *
             Mh[(((long)(b * 8 + h)) * 640 + q) * 512 + d];
    const float f = use_fk ? fk[r * 512 + d] : 0.f;
    v[j] = f + acc * (1.f / 512.f);
  }
  float s = v[0] + v[1];
  for (int o = 32; o; o >>= 1) s += __shfl_down(s, o, 64);
  if ((t & 63) == 0) red[t >> 6] = s;
  __syncthreads();
  const float mu = (red[0] + red[1] + red[2] + red[3]) * (1.f / 512.f);
  __syncthreads();
  const float d0 = v[0] - mu, d1 = v[1] - mu;
  s = d0 * d0 + d1 * d1;
  for (int o = 32; o; o >>= 1) s += __shfl_down(s, o, 64);
  if ((t & 63) == 0) red[t >> 6] = s;
  __syncthreads();
  const float var = (red[0] + red[1] + red[2] + red[3]) * (1.f / 512.f);
  const float rs = rsqrtf(var + 1e-5f);
  hout[r * 512 + t]       = f2bf(d0 * rs * lng[l * 512 + t]);
  hout[r * 512 + t + 256] = f2bf(d1 * rs * lng[l * 512 + t + 256]);
}

extern "C" void kernel_launch(void* const* d_in, const int* in_sizes, int n_in,
                              void* d_out, int out_size, void* d_ws, size_t ws_size,
                              hipStream_t stream)
{
  const int*   x   = (const int*)d_in[0];
  const float* We  = (const float*)d_in[1];
  const float* Wp  = (const float*)d_in[2];
  const float* Wq  = (const float*)d_in[3];
  const float* Wk  = (const float*)d_in[4];
  const float* Wv  = (const float*)d_in[5];
  const float* Alr = (const float*)d_in[6];
  const float* Blr = (const float*)d_in[7];
  const float* lng = (const float*)d_in[8];
  const float* W1  = (const float*)d_in[9];
  const float* W2  = (const float*)d_in[10];
  float* out = (float*)d_out;

  char* ws = (char*)d_ws;
  size_t off = 0;
  auto alloc = [&](size_t bytes) {
    char* p = ws + off; off += (bytes + 255) & ~(size_t)255; return p;
  };
  u16*   Web    = (u16*)  alloc(32000l * 512 * 2);
  u16*   WeT    = (u16*)  alloc(512l * 32000 * 2);
  u16*   attn   = (u16*)  alloc(8l * 640 * 512 * 2);
  float* e      = (float*)alloc(2048l * 512 * 4);
  float* colsum = (float*)alloc(512 * 4);
  float* csum   = (float*)alloc(4 * 512 * 4);
  float* rowsum = (float*)alloc(2048 * 4);
  u16*   diffT  = (u16*)  alloc(4l * 512 * 512 * 2);
  u16*   hpack  = (u16*)  alloc(2176l * 512 * 2);
  u16*   h1pack = (u16*)  alloc(2176l * 2048 * 2);
  float* fk     = (float*)alloc(2176l * 512 * 4);
  u16*   fpack  = (u16*)  alloc(2048l * 512 * 2);
  u16*   W1b    = (u16*)  alloc(2l * 2048 * 512 * 2);
  u16*   W2b    = (u16*)  alloc(2l * 512 * 2048 * 2);
  char*  big    =         alloc(2048l * 32000 * 2 + 8l * 2048 * 512 * 4);
  // big-region aliases (lifetimes disjoint):
  u16*   T      = (u16*)big;                                   // layer-1 T (131 MB)
  float* part   = (float*)(big + 2048l * 32000 * 2);           // split-K partials
  u16*   Qp     = (u16*)big;                                   // pre-layer only
  u16*   Kp     = (u16*)(big + 8l * 640 * 512 * 2);
  float* scores = (float*)(big + 8l * 640 * 512 * 2 + 8l * 512 * 512 * 2);
  float* Mh     = (float*)big;                                 // per-layer attn@diff

  if (off > ws_size) return;  // workspace too small -> loud validation failure

  // ---- prep ----
  hipMemsetAsync(colsum, 0, 512 * 4, stream);
  prep_we_k<<<dim3(500, 8), 256, 0, stream>>>(We, Web, WeT, colsum);
  cast_k<<<8192, 256, 0, stream>>>(W1, W2, W1b, W2b, 2 * 2048 * 512);
  gather_e_k<<<2048, 256, 0, stream>>>(x, We, e);
  qkpack_k<<<dim3(513, 8), 256, 0, stream>>>(Wp, Wq, Wk, Qp, Kp);
  gemm_nt<0><<<dim3(5, 4, 8), 256, 0, stream>>>(Qp, Kp, scores, nullptr,
      512, 512, 512, 16, 640l * 512, 512l * 512, 640l * 512, 0);
  softmax_k<<<dim3(513, 8), 256, 0, stream>>>(scores, attn);

  for (int l = 0; l < 2; ++l) {
    if (l == 1) {
      // T = exp(clip(f @ We^T)) , bf16
      gemm_nt<1><<<dim3(16, 250), 256, 0, stream>>>(fpack, Web, nullptr, T,
          512, 512, 32000, 16, 0, 0, 0, 0);
      rowsumT_k<<<2048, 256, 0, stream>>>(T, rowsum);
      // E partials = T @ We (split-K over 8 chunks of 4000)
      gemm_nt<0><<<dim3(16, 4, 8), 256, 0, stream>>>(T, WeT, part, nullptr,
          32000, 32000, 512, 125, 4000l, 4000l, 2048l * 512, 0);
    }
    hipMemsetAsync(csum, 0, 4 * 512 * 4, stream);
    if (l == 0)
      diff_k<0><<<dim3(8, 8, 4), 256, 0, stream>>>(e, nullptr, nullptr, colsum, diffT, csum);
    else
      diff_k<1><<<dim3(8, 8, 4), 256, 0, stream>>>(e, part, rowsum, nullptr, diffT, csum);
    // Mh[b,h] = attn[h] @ diff[b]
    gemm_nt<0><<<dim3(5, 4, 32), 256, 0, stream>>>(attn, diffT, Mh, nullptr,
        512, 512, 512, 16, 640l * 512, 512l * 512, 640l * 512, 1);
    delta_ln_k<<<dim3(513, 4), 256, 0, stream>>>(Mh, csum, fk, Wv, Alr, Blr, lng,
        hpack, l, l);
    // FF
    gemm_nt<2><<<dim3(17, 16), 256, 0, stream>>>(hpack, W1b + (size_t)l * 2048 * 512,
        nullptr, h1pack, 512, 512, 2048, 16, 0, 0, 0, 0);
    gemm_nt<3><<<dim3(17, 4), 256, 0, stream>>>(h1pack, W2b + (size_t)l * 512 * 2048,
        fk, fpack, 2048, 2048, 512, 64, 0, 0, 0, 0);
  }

  // logits = f @ We^T  (f32, direct to d_out)
  gemm_nt<0><<<dim3(16, 250), 256, 0, stream>>>(fpack, Web, out, nullptr,
      512, 512, 32000, 16, 0, 0, 0, 0);
}

// Round 2
// 655.158 us; speedup vs baseline: 1.0414x; 1.0414x over previous
//
#include <hip/hip_runtime.h>
#include <hip/hip_bf16.h>

typedef unsigned short u16;
typedef __bf16 bf16x8 __attribute__((ext_vector_type(8)));
typedef float f32x4 __attribute__((ext_vector_type(4)));

__device__ __forceinline__ float bf2f(u16 u) {
  union { unsigned int u; float f; } x; x.u = ((unsigned int)u) << 16; return x.f;
}
__device__ __forceinline__ u16 f2bf(float f) {  // round-to-nearest-even bf16
  union { float f; unsigned int u; } x; x.f = f;
  unsigned int r = x.u + 0x7fffu + ((x.u >> 16) & 1u);
  return (u16)(r >> 16);
}

__device__ __forceinline__ void gload16(const void* g, void* l) {
  __builtin_amdgcn_global_load_lds((__attribute__((address_space(1))) void*)g,
                                   (__attribute__((address_space(3))) void*)l, 16, 0, 0);
}

#define BAR()   __builtin_amdgcn_s_barrier()
#define FENCE() asm volatile("" ::: "memory")
#define VMCNT4() asm volatile("s_waitcnt vmcnt(4)" ::: "memory")

// ===========================================================================
// 256x256 8-phase GEMM (T2 swizzle + T3/T4 counted vmcnt + T5 setprio + T1 XCD)
// C[m,n] = sum_k A[m,k]*B[n,k]; A:(M,K) row-major, B:(N,K) row-major, bf16.
// M multiple of 256, N multiple of 256, K = ktiles*64 (ktiles even).
// 512 threads = 8 waves as 2(M)x4(N); per-wave output 128x64; acc[8][4] f32x4.
// EPI 0: f32 C ; EPI 1: bf16 exp(clip(v,-10,10)) -> Cb.
// ===========================================================================
template<int EPI>
__global__ __launch_bounds__(512, 2) void gemm256(
    const u16* __restrict__ A, const u16* __restrict__ B,
    float* __restrict__ C, u16* __restrict__ Cb,
    int lda, int ldb, int ldc, int ktiles)
{
  // [dbuf][op A=0/B=1][half][row 0..127][col 0..63] = 128 KiB
  __shared__ __attribute__((aligned(16))) u16 lds[2][2][2][128][64];

  // T1: bijective XCD swizzle (m204), m-block fastest within an XCD chunk.
  const int nwg = gridDim.x * gridDim.y;
  const int flat = blockIdx.y * gridDim.x + blockIdx.x;
  const int qq = nwg >> 3, rr = nwg & 7;
  const int xcd = flat & 7, sidx = flat >> 3;
  const int u = (xcd < rr) ? xcd * (qq + 1) + sidx
                           : rr * (qq + 1) + (xcd - rr) * qq + sidx;
  const int mbase = (u % gridDim.x) * 256;
  const int nbase = (u / gridDim.x) * 256;

  const int tid = threadIdx.x;
  const int lane = tid & 63;
  const int w = tid >> 6;
  const int wr = w >> 2;          // 0..1  (M wave row)
  const int wc = w & 3;           // 0..3  (N wave col)
  const int fr = lane & 15;
  const int fko2 = (lane >> 4) * 16;          // k byte offset within 32-elem frag
  const int sx = ((fr >> 2) & 1) << 5;        // st_16x32 read swizzle (bit9->bit5)

  // Stage addressing: linear LDS dest o, pre-swizzled global source swz(o).
  const int o0 = tid * 16, o1 = 8192 + tid * 16;
  const int sxs = ((tid >> 5) & 1) << 5;
  const int sq0 = o0 ^ sxs, sq1 = o1 ^ sxs;
  const int srow0 = sq0 >> 7, scol0 = (sq0 & 127) >> 1;
  const int srow1 = sq1 >> 7, scol1 = (sq1 & 127) >> 1;

  f32x4 acc[8][4];
  #pragma unroll
  for (int m = 0; m < 8; ++m)
    #pragma unroll
    for (int n = 0; n < 4; ++n) acc[m][n] = (f32x4){0.f, 0.f, 0.f, 0.f};

  // stage pair pr (A-half pr + B-half pr) of K-tile kt (clamped; uniform order)
  auto stg = [&](int kt, int pr) {
    const int kc = kt < ktiles ? kt : ktiles - 1;
    const int p = kc & 1;
    const u16* gA = A + (size_t)(mbase + pr * 128) * lda + (size_t)kc * 64;
    const u16* gB = B + (size_t)(nbase + pr * 128) * ldb + (size_t)kc * 64;
    char* lA = (char*)&lds[p][0][pr][0][0];
    char* lB = (char*)&lds[p][1][pr][0][0];
    gload16(gA + (size_t)srow0 * lda + scol0, lA + o0);
    gload16(gA + (size_t)srow1 * lda + scol1, lA + o1);
    gload16(gB + (size_t)srow0 * ldb + scol0, lB + o0);
    gload16(gB + (size_t)srow1 * ldb + scol1, lB + o1);
  };

  auto rdA = [&](const char* aH, int mb, bf16x8* dst) {
    #pragma unroll
    for (int m = 0; m < 4; ++m)
      #pragma unroll
      for (int ks = 0; ks < 2; ++ks)
        dst[m * 2 + ks] = *(const bf16x8*)(aH +
            ((((mb + m) * 16 + fr) * 128 + ks * 64 + fko2) ^ sx));
  };
  auto rdB = [&](const char* bH, int nb, bf16x8* dst) {
    #pragma unroll
    for (int n = 0; n < 2; ++n)
      #pragma unroll
      for (int ks = 0; ks < 2; ++ks)
        dst[n * 2 + ks] = *(const bf16x8*)(bH +
            ((((wc & 1) * 64 + (nb + n) * 16 + fr) * 128 + ks * 64 + fko2) ^ sx));
  };
  auto mfmaQ = [&](const bf16x8* aa, const bf16x8* bb, int mb, int nb) {
    #pragma unroll
    for (int m = 0; m < 4; ++m)
      #pragma unroll
      for (int n = 0; n < 2; ++n)
        #pragma unroll
        for (int ks = 0; ks < 2; ++ks)
          acc[mb + m][nb + n] = __builtin_amdgcn_mfma_f32_16x16x32_bf16(
              aa[m * 2 + ks], bb[n * 2 + ks], acc[mb + m][nb + n], 0, 0, 0);
  };

  // 4-phase group computing one K-tile from dbuf p; stages (ktA,pair1)@ph1
  // and (ktB,pair0)@ph4 with vmcnt(4) checkpoint at ph4.
  auto group = [&](int p, int ktA, int ktB) {
    const char* aH = (const char*)&lds[p][0][wr][0][0];
    const char* bH = (const char*)&lds[p][1][wc >> 1][0][0];
    bf16x8 a[8], b[8];
    // ph1: A m0-3, B n0-1 ; MFMA quad (m0-3 x n0-1)
    rdA(aH, 0, a);
    rdB(bH, 0, b);
    stg(ktA, 1);
    BAR(); FENCE();
    __builtin_amdgcn_s_setprio(1);
    mfmaQ(a, b, 0, 0);
    __builtin_amdgcn_s_setprio(0);
    BAR(); FENCE();
    // ph2: B n2-3 ; MFMA (m0-3 x n2-3)
    rdB(bH, 2, b + 4);
    BAR(); FENCE();
    __builtin_amdgcn_s_setprio(1);
    mfmaQ(a, b + 4, 0, 2);
    __builtin_amdgcn_s_setprio(0);
    BAR(); FENCE();
    // ph3: A m4-7 ; MFMA (m4-7 x n2-3)
    rdA(aH, 4, a);
    BAR(); FENCE();
    __builtin_amdgcn_s_setprio(1);
    mfmaQ(a, b + 4, 4, 2);
    __builtin_amdgcn_s_setprio(0);
    BAR(); FENCE();
    // ph4: stage next pair ; MFMA (m4-7 x n0-1) ; vmcnt checkpoint
    stg(ktB, 0);
    BAR(); FENCE();
    __builtin_amdgcn_s_setprio(1);
    mfmaQ(a, b, 4, 0);
    __builtin_amdgcn_s_setprio(0);
    VMCNT4();
    BAR(); FENCE();
  };

  // Prologue: tile0 complete + tile1 pair0 in flight.
  stg(0, 0); stg(0, 1); stg(1, 0);
  VMCNT4();
  BAR(); FENCE();

  const int niters = ktiles >> 1;
  for (int it = 0; it < niters; ++it) {
    const int t0 = it * 2;
    group(0, t0 + 1, t0 + 2);   // compute tile t0   (buf0)
    group(1, t0 + 2, t0 + 3);   // compute tile t0+1 (buf1)
  }

  // Epilogue: C/D layout col=lane&15, row=(lane>>4)*4+j
  #pragma unroll
  for (int m = 0; m < 8; ++m) {
    const int r0 = mbase + wr * 128 + m * 16 + (lane >> 4) * 4;
    #pragma unroll
    for (int n = 0; n < 4; ++n) {
      const int c = nbase + wc * 64 + n * 16 + (lane & 15);
      #pragma unroll
      for (int j = 0; j < 4; ++j) {
        const float v = acc[m][n][j];
        const long idx = (long)(r0 + j) * ldc + c;
        if (EPI == 0) {
          C[idx] = v;
        } else {
          const float cv = fminf(fmaxf(v, -10.f), 10.f);
          Cb[idx] = f2bf(__expf(cv));
        }
      }
    }
  }
}

// ---------------------------------------------------------------------------
// 128x128 m97-structure NT GEMM (unchanged from round 1) for the smaller /
// long-K GEMMs. EPI: 0=f32, 1=exp-clip bf16, 2=gelu bf16, 3=f32 fk + bf16 pack.
// ---------------------------------------------------------------------------
template<int EPI>
__global__ __launch_bounds__(256) void gemm_nt(
    const u16* __restrict__ A, const u16* __restrict__ B,
    float* __restrict__ C, u16* __restrict__ Cb,
    int lda, int ldb, int ldc, int ksteps,
    long aZ, long bZ, long cZ, int zmode)
{
  __shared__ __attribute__((aligned(16))) u16 sA[128 * 32];
  __shared__ __attribute__((aligned(16))) u16 sB[128 * 32];
  const int t = threadIdx.x;
  const int mbase = blockIdx.x * 128;
  const int nbase = blockIdx.y * 128;
  const int z = blockIdx.z;
  long aoff, boff;
  if (zmode == 1) { aoff = (long)(z & 7) * aZ; boff = (long)(z >> 3) * bZ; }
  else            { aoff = (long)z * aZ;       boff = (long)z * bZ; }
  const long coff = (long)z * cZ;
  const u16* Ab = A + aoff + (long)mbase * lda;
  const u16* Bb = B + boff + (long)nbase * ldb;

  const int srow = t >> 2;
  const int scol = (t & 3) * 8;
  const int lane = t & 63;
  const int w = t >> 6;
  const int wrow = (w >> 1) * 64;
  const int wcol = (w & 1) * 64;
  const int fr  = lane & 15;
  const int fko = (lane >> 4) * 8;

  f32x4 acc[4][4];
  #pragma unroll
  for (int m = 0; m < 4; ++m)
    #pragma unroll
    for (int n = 0; n < 4; ++n) acc[m][n] = (f32x4){0.f, 0.f, 0.f, 0.f};

  for (int ks = 0; ks < ksteps; ++ks) {
    const int kb = ks * 32;
    #pragma unroll
    for (int c = 0; c < 2; ++c) {
      gload16(Ab + (long)(c * 64 + srow) * lda + kb + scol, &sA[(c * 64 + srow) * 32 + scol]);
      gload16(Bb + (long)(c * 64 + srow) * ldb + kb + scol, &sB[(c * 64 + srow) * 32 + scol]);
    }
    __syncthreads();
    bf16x8 af[4], bfg[4];
    #pragma unroll
    for (int m = 0; m < 4; ++m) af[m]  = *(const bf16x8*)&sA[(wrow + m * 16 + fr) * 32 + fko];
    #pragma unroll
    for (int n = 0; n < 4; ++n) bfg[n] = *(const bf16x8*)&sB[(wcol + n * 16 + fr) * 32 + fko];
    #pragma unroll
    for (int m = 0; m < 4; ++m)
      #pragma unroll
      for (int n = 0; n < 4; ++n)
        acc[m][n] = __builtin_amdgcn_mfma_f32_16x16x32_bf16(af[m], bfg[n], acc[m][n], 0, 0, 0);
    __syncthreads();
  }

  #pragma unroll
  for (int m = 0; m < 4; ++m) {
    const int r0 = mbase + wrow + m * 16 + (lane >> 4) * 4;
    #pragma unroll
    for (int n = 0; n < 4; ++n) {
      const int c = nbase + wcol + n * 16 + (lane & 15);
      #pragma unroll
      for (int j = 0; j < 4; ++j) {
        const float v = acc[m][n][j];
        const int r = r0 + j;
        const long idx = coff + (long)r * ldc + c;
        if (EPI == 0) {
          C[idx] = v;
        } else if (EPI == 1) {
          float cv = fminf(fmaxf(v, -10.f), 10.f);
          Cb[idx] = f2bf(__expf(cv));
        } else if (EPI == 2) {
          Cb[idx] = f2bf(0.5f * v * (1.f + erff(v * 0.70710678118654752f)));
        } else {
          C[(long)r * 512 + c] = v;
          int b = r / 513;
          int s = r - b * 513;
          if (r < 2052 && s < 512) Cb[((long)(b * 512 + s)) * 512 + c] = f2bf(v);
        }
      }
    }
  }
}

// --------- W_e prep: bf16 cast, transposed bf16 copy, column sums ----------
__global__ void prep_we_k(const float* __restrict__ We, u16* __restrict__ Web,
                          u16* __restrict__ WeT, float* __restrict__ colsum)
{
  __shared__ float tile[64][65];
  const int v0 = blockIdx.x * 64, d0 = blockIdx.y * 64;
  const int t = threadIdx.x;
  const int c = t & 63;
  #pragma unroll
  for (int rr = 0; rr < 64; rr += 4) {
    const int row = rr + (t >> 6);
    const float x = We[(long)(v0 + row) * 512 + d0 + c];
    Web[(long)(v0 + row) * 512 + d0 + c] = f2bf(x);
    tile[row][c] = x;
  }
  __syncthreads();
  #pragma unroll
  for (int rr = 0; rr < 64; rr += 4) {
    const int drow = rr + (t >> 6);
    WeT[(long)(d0 + drow) * 32000 + v0 + c] = f2bf(tile[c][drow]);
  }
  if (t < 64) {
    float s = 0.f;
    #pragma unroll
    for (int i = 0; i < 64; ++i) s += tile[i][t];
    atomicAdd(&colsum[d0 + t], s);
  }
}

__global__ void cast_k(const float* __restrict__ a, const float* __restrict__ b,
                       u16* __restrict__ ab, u16* __restrict__ bb, int n)
{
  const int i = blockIdx.x * 256 + threadIdx.x;
  if (i < n) { ab[i] = f2bf(a[i]); bb[i] = f2bf(b[i]); }
}

__global__ void gather_e_k(const int* __restrict__ x, const float* __restrict__ We,
                           float* __restrict__ e)
{
  const long r = blockIdx.x;
  const long v = x[r];
  const int t = threadIdx.x;
  e[r * 512 + t]       = We[v * 512 + t];
  e[r * 512 + t + 256] = We[v * 512 + t + 256];
}

__global__ void qkpack_k(const float* __restrict__ Wp, const float* __restrict__ Wq,
                         const float* __restrict__ Wk, u16* __restrict__ Qp,
                         u16* __restrict__ Kp)
{
  const int q = blockIdx.x;
  const int h = blockIdx.y;
  const int t = threadIdx.x;
  #pragma unroll
  for (int j = 0; j < 2; ++j) {
    const int d = t + j * 256;
    const float pv = Wp[(long)q * 512 + d];
    Qp[((long)h * 640 + q) * 512 + d] = f2bf(pv * Wq[h * 512 + d]);
    if (q < 512) Kp[((long)h * 512 + q) * 512 + d] = f2bf(pv * Wk[h * 512 + d]);
  }
}

__global__ void softmax_k(const float* __restrict__ scores, u16* __restrict__ attn)
{
  const int q = blockIdx.x;
  const int h = blockIdx.y;
  const float* row = scores + ((long)h * 640 + q) * 512;
  u16* orow = attn + ((long)h * 640 + q) * 512;
  const int t = threadIdx.x;
  const float v0 = row[t], v1 = row[t + 256];
  __shared__ float red[4];
  float m = fmaxf(v0, v1);
  for (int o = 32; o; o >>= 1) m = fmaxf(m, __shfl_down(m, o, 64));
  if ((t & 63) == 0) red[t >> 6] = m;
  __syncthreads();
  m = fmaxf(fmaxf(red[0], red[1]), fmaxf(red[2], red[3]));
  __syncthreads();
  const float e0 = __expf(v0 - m), e1 = __expf(v1 - m);
  float s = e0 + e1;
  for (int o = 32; o; o >>= 1) s += __shfl_down(s, o, 64);
  if ((t & 63) == 0) red[t >> 6] = s;
  __syncthreads();
  s = red[0] + red[1] + red[2] + red[3];
  const float inv = 1.f / s;
  orow[t]       = f2bf(e0 * inv);
  orow[t + 256] = f2bf(e1 * inv);
}

__global__ void rowsumT_k(const u16* __restrict__ T, float* __restrict__ rowsum)
{
  const long r = blockIdx.x;
  const u16* row = T + r * 32000;
  const int t = threadIdx.x;
  float s = 0.f;
  for (int i = t * 8; i < 32000; i += 2048) {
    uint4 a = *(const uint4*)(row + i);
    const u16* pu = (const u16*)&a;
    #pragma unroll
    for (int j = 0; j < 8; ++j) s += bf2f(pu[j]);
  }
  __shared__ float red[4];
  for (int o = 32; o; o >>= 1) s += __shfl_down(s, o, 64);
  if ((t & 63) == 0) red[t >> 6] = s;
  __syncthreads();
  if (t == 0) rowsum[r] = red[0] + red[1] + red[2] + red[3];
}

template<int USE_E>
__global__ void diff_k(const float* __restrict__ e, const float* __restrict__ part,
                       const float* __restrict__ rowsum, const float* __restrict__ colsum,
                       u16* __restrict__ diffT, float* __restrict__ csum)
{
  __shared__ float tile[64][65];
  const int s0 = blockIdx.x * 64, d0 = blockIdx.y * 64, b = blockIdx.z;
  const int t = threadIdx.x;
  const int c = t & 63;
  #pragma unroll
  for (int rr = 0; rr < 64; rr += 4) {
    const int srow = rr + (t >> 6);
    const long r = (long)b * 512 + s0 + srow;
    float E;
    if (USE_E) {
      float s = 0.f;
      #pragma unroll
      for (int p = 0; p < 8; ++p) s += part[((long)p * 2048 + r) * 512 + d0 + c];
      E = s / (rowsum[r] + 1e-8f);
    } else {
      E = colsum[d0 + c] * (1.0f / 32000.0f);
    }
    tile[srow][c] = e[r * 512 + d0 + c] - E;
  }
  __syncthreads();
  #pragma unroll
  for (int rr = 0; rr < 64; rr += 4) {
    const int drow = rr + (t >> 6);
    diffT[((long)b * 512 + d0 + drow) * 512 + s0 + c] = f2bf(tile[c][drow]);
  }
  if (t < 64) {
    float s = 0.f;
    #pragma unroll
    for (int i = 0; i < 64; ++i) s += tile[i][t];
    atomicAdd(&csum[b * 512 + d0 + t], s);
  }
}

__global__ void delta_ln_k(const float* __restrict__ Mh, const float* __restrict__ csum,
                           const float* __restrict__ fk, const float* __restrict__ Wv,
                           const float* __restrict__ Alr, const float* __restrict__ Blr,
                           const float* __restrict__ lng, u16* __restrict__ hout,
                           int l, int use_fk)
{
  const int q = blockIdx.x;
  const int b = blockIdx.y;
  const long r = (long)b * 513 + q;
  const int t = threadIdx.x;
  __shared__ float red[4];
  float v[2];
  #pragma unroll
  for (int j = 0; j < 2; ++j) {
    const int d = t + j * 256;
    float acc = Blr[l] * csum[b * 512 + d];
    #pragma unroll
    for (int h = 0; h < 8; ++h)
      acc += Alr[l * 8 + h] * Wv[(l * 8 + h) * 512 + d] *
             Mh[(((long)(b * 8 + h)) * 640 + q) * 512 + d];
    const float f = use_fk ? fk[r * 512 + d] : 0.f;
    v[j] = f + acc * (1.f / 512.f);
  }
  float s = v[0] + v[1];
  for (int o = 32; o; o >>= 1) s += __shfl_down(s, o, 64);
  if ((t & 63) == 0) red[t >> 6] = s;
  __syncthreads();
  const float mu = (red[0] + red[1] + red[2] + red[3]) * (1.f / 512.f);
  __syncthreads();
  const float d0 = v[0] - mu, d1 = v[1] - mu;
  s = d0 * d0 + d1 * d1;
  for (int o = 32; o; o >>= 1) s += __shfl_down(s, o, 64);
  if ((t & 63) == 0) red[t >> 6] = s;
  __syncthreads();
  const float var = (red[0] + red[1] + red[2] + red[3]) * (1.f / 512.f);
  const float rs = rsqrtf(var + 1e-5f);
  hout[r * 512 + t]       = f2bf(d0 * rs * lng[l * 512 + t]);
  hout[r * 512 + t + 256] = f2bf(d1 * rs * lng[l * 512 + t + 256]);
}

extern "C" void kernel_launch(void* const* d_in, const int* in_sizes, int n_in,
                              void* d_out, int out_size, void* d_ws, size_t ws_size,
                              hipStream_t stream)
{
  const int*   x   = (const int*)d_in[0];
  const float* We  = (const float*)d_in[1];
  const float* Wp  = (const float*)d_in[2];
  const float* Wq  = (const float*)d_in[3];
  const float* Wk  = (const float*)d_in[4];
  const float* Wv  = (const float*)d_in[5];
  const float* Alr = (const float*)d_in[6];
  const float* Blr = (const float*)d_in[7];
  const float* lng = (const float*)d_in[8];
  const float* W1  = (const float*)d_in[9];
  const float* W2  = (const float*)d_in[10];
  float* out = (float*)d_out;

  char* ws = (char*)d_ws;
  size_t off = 0;
  auto alloc = [&](size_t bytes) {
    char* p = ws + off; off += (bytes + 255) & ~(size_t)255; return p;
  };
  u16*   Web    = (u16*)  alloc(32000l * 512 * 2);
  u16*   WeT    = (u16*)  alloc(512l * 32000 * 2);
  u16*   attn   = (u16*)  alloc(8l * 640 * 512 * 2);
  float* e      = (float*)alloc(2048l * 512 * 4);
  float* colsum = (float*)alloc(512 * 4);
  float* csum   = (float*)alloc(4 * 512 * 4);
  float* rowsum = (float*)alloc(2048 * 4);
  u16*   diffT  = (u16*)  alloc(4l * 512 * 512 * 2);
  u16*   hpack  = (u16*)  alloc(2176l * 512 * 2);
  u16*   h1pack = (u16*)  alloc(2176l * 2048 * 2);
  float* fk     = (float*)alloc(2176l * 512 * 4);
  u16*   fpack  = (u16*)  alloc(2048l * 512 * 2);
  u16*   W1b    = (u16*)  alloc(2l * 2048 * 512 * 2);
  u16*   W2b    = (u16*)  alloc(2l * 512 * 2048 * 2);
  char*  big    =         alloc(2048l * 32000 * 2 + 8l * 2048 * 512 * 4);
  u16*   T      = (u16*)big;
  float* part   = (float*)(big + 2048l * 32000 * 2);
  u16*   Qp     = (u16*)big;
  u16*   Kp     = (u16*)(big + 8l * 640 * 512 * 2);
  float* scores = (float*)(big + 8l * 640 * 512 * 2 + 8l * 512 * 512 * 2);
  float* Mh     = (float*)big;

  if (off > ws_size) return;

  // ---- prep ----
  hipMemsetAsync(colsum, 0, 512 * 4, stream);
  prep_we_k<<<dim3(500, 8), 256, 0, stream>>>(We, Web, WeT, colsum);
  cast_k<<<8192, 256, 0, stream>>>(W1, W2, W1b, W2b, 2 * 2048 * 512);
  gather_e_k<<<2048, 256, 0, stream>>>(x, We, e);
  qkpack_k<<<dim3(513, 8), 256, 0, stream>>>(Wp, Wq, Wk, Qp, Kp);
  gemm_nt<0><<<dim3(5, 4, 8), 256, 0, stream>>>(Qp, Kp, scores, nullptr,
      512, 512, 512, 16, 640l * 512, 512l * 512, 640l * 512, 0);
  softmax_k<<<dim3(513, 8), 256, 0, stream>>>(scores, attn);

  for (int l = 0; l < 2; ++l) {
    if (l == 1) {
      // T = exp(clip(f @ We^T)) , bf16  — 256^2 8-phase kernel
      gemm256<1><<<dim3(8, 125), 512, 0, stream>>>(fpack, Web, nullptr, T,
          512, 512, 32000, 8);
      rowsumT_k<<<2048, 256, 0, stream>>>(T, rowsum);
      // E partials = T @ We (split-K over 8 chunks of 4000), long-K 128^2
      gemm_nt<0><<<dim3(16, 4, 8), 256, 0, stream>>>(T, WeT, part, nullptr,
          32000, 32000, 512, 125, 4000l, 4000l, 2048l * 512, 0);
    }
    hipMemsetAsync(csum, 0, 4 * 512 * 4, stream);
    if (l == 0)
      diff_k<0><<<dim3(8, 8, 4), 256, 0, stream>>>(e, nullptr, nullptr, colsum, diffT, csum);
    else
      diff_k<1><<<dim3(8, 8, 4), 256, 0, stream>>>(e, part, rowsum, nullptr, diffT, csum);
    gemm_nt<0><<<dim3(5, 4, 32), 256, 0, stream>>>(attn, diffT, Mh, nullptr,
        512, 512, 512, 16, 640l * 512, 512l * 512, 640l * 512, 1);
    delta_ln_k<<<dim3(513, 4), 256, 0, stream>>>(Mh, csum, fk, Wv, Alr, Blr, lng,
        hpack, l, l);
    gemm_nt<2><<<dim3(17, 16), 256, 0, stream>>>(hpack, W1b + (size_t)l * 2048 * 512,
        nullptr, h1pack, 512, 512, 2048, 16, 0, 0, 0, 0);
    gemm_nt<3><<<dim3(17, 4), 256, 0, stream>>>(h1pack, W2b + (size_t)l * 512 * 2048,
        fk, fpack, 2048, 2048, 512, 64, 0, 0, 0, 0);
  }

  // logits = f @ We^T  (f32, direct to d_out) — 256^2 8-phase kernel
  gemm256<0><<<dim3(8, 125), 512, 0, stream>>>(fpack, Web, out, nullptr,
      512, 512, 32000, 8);
}